// Round 6
// baseline (579.863 us; speedup 1.0000x reference)
//
#include <hip/hip_runtime.h>
#include <stdint.h>

#define B_N 2048
#define Z_N 128
#define A_N 4
#define D_N 50000
#define D_PAD 53248    // 64 spans * 832 ; pad rows are exact zeros
#define EPS_F 1e-8f

#define TILE_B 128     // 8 waves x 16 samples/wave
#define KT 64          // keys per barrier interval (two 32-key MFMA steps)
#define NSPLIT 64      // divisible by 8 (XCD swizzle encoding)
#define SPAN 832       // 13*64 ; 64 spans cover 53248
#define NITER 13
#define VL_S 72        // shorts/row: 16B-aligned, 36 dw == 4 (mod 32) -> 2-way/phase (free)

#define NORM_BLOCKS 53760   // (A_N*D_PAD + B_N)/4
#define VT_BX 832           // D_PAD/64

typedef __attribute__((ext_vector_type(8))) short short8;   // 8 bf16
typedef __attribute__((ext_vector_type(4))) float f32x4;
typedef __attribute__((ext_vector_type(2))) unsigned int u32x2;

__device__ __forceinline__ unsigned short f2bf(float f) {
  unsigned int u = __builtin_bit_cast(unsigned int, f);
  u += 0x7FFFu + ((u >> 16) & 1u);   // RNE
  return (unsigned short)(u >> 16);
}

__device__ __forceinline__ void plswap32(unsigned int& a, unsigned int& b) {
#if __has_builtin(__builtin_amdgcn_permlane32_swap)
  u32x2 r = __builtin_amdgcn_permlane32_swap(a, b, false, false);
  a = r[0]; b = r[1];
#else
  asm volatile("v_permlane32_swap_b32 %0, %1" : "+v"(a), "+v"(b));
#endif
}
__device__ __forceinline__ void plswap16(unsigned int& a, unsigned int& b) {
#if __has_builtin(__builtin_amdgcn_permlane16_swap)
  u32x2 r = __builtin_amdgcn_permlane16_swap(a, b, false, false);
  a = r[0]; b = r[1];
#else
  asm volatile("v_permlane16_swap_b32 %0, %1" : "+v"(a), "+v"(b));
#endif
}

// ------------------------------------------------------------------
// P: fused prep. Blocks [0, NORM_BLOCKS): normalize keys -> bf16
//    kn[a][d_pad][z] (pad rows = 0) and batch_x -> qnb.
//    Blocks >= NORM_BLOCKS: transpose vals -> bf16 vt[a][z][d_pad].
// ------------------------------------------------------------------
__global__ void k_prep(const float* __restrict__ keys, const float* __restrict__ x,
                       const float* __restrict__ vals,
                       unsigned short* __restrict__ kn, unsigned short* __restrict__ qnb,
                       unsigned short* __restrict__ vt) {
  if (blockIdx.x < NORM_BLOCKS) {
    int w = threadIdx.x >> 6, lane = threadIdx.x & 63;
    int row = blockIdx.x * 4 + w;      // < A*D_PAD + B
    const float* src;
    unsigned short* dst;
    if (row >= A_N * D_PAD) {          // query row
      int r = row - A_N * D_PAD;
      src = x + (size_t)r * Z_N;
      dst = qnb + (size_t)r * Z_N;
    } else {
      int a = row / D_PAD, d = row - a * D_PAD;
      dst = kn + (size_t)row * Z_N;
      if (d >= D_N) { ((unsigned int*)dst)[lane] = 0u; return; }   // zero pad row
      src = keys + ((size_t)a * D_N + d) * Z_N;
    }
    const float2 v = ((const float2*)src)[lane];
    float ss = v.x * v.x + v.y * v.y;
#pragma unroll
    for (int m = 1; m < 64; m <<= 1) ss += __shfl_xor(ss, m);
    float inv = 1.0f / (sqrtf(ss) + EPS_F);
    unsigned int packed = ((unsigned int)f2bf(v.y * inv) << 16) | f2bf(v.x * inv);
    ((unsigned int*)dst)[lane] = packed;
    return;
  }
  // ---- vals transpose ----
  __shared__ float tile[64][65];
  int b = blockIdx.x - NORM_BLOCKS;        // 0 .. VT_BX*2*A_N-1
  int bx = b % VT_BX, rest = b / VT_BX;
  int by = rest & 1, a = rest >> 1;
  int d0 = bx * 64, z0 = by * 64;
  int t = threadIdx.x;
  int r = t >> 4, c4 = (t & 15) * 4;
#pragma unroll
  for (int i = 0; i < 4; ++i) {
    int dr = r + i * 16, d = d0 + dr;
    float4 v = {0.f, 0.f, 0.f, 0.f};
    if (d < D_N) v = *(const float4*)(vals + ((size_t)a * D_N + d) * Z_N + z0 + c4);
    tile[dr][c4 + 0] = v.x; tile[dr][c4 + 1] = v.y;
    tile[dr][c4 + 2] = v.z; tile[dr][c4 + 3] = v.w;
  }
  __syncthreads();
  int zz = t >> 2, dg = (t & 3) * 16;
  union { unsigned short u[16]; uint4 q[2]; } pk;
#pragma unroll
  for (int j = 0; j < 16; ++j) pk.u[j] = f2bf(tile[dg + j][zz]);
  unsigned short* dst = vt + ((size_t)a * Z_N + z0 + zz) * D_PAD + d0 + dg;
  ((uint4*)dst)[0] = pk.q[0];
  ((uint4*)dst)[1] = pk.q[1];
}

// ------------------------------------------------------------------
// R: single-block routing + work list (TILE_B = 128). Item index
//    encodes XCD-pinned span-major order: i = (c&7) + 8*((c>>3)*T + j).
// ------------------------------------------------------------------
__global__ void k_route(const int* __restrict__ act, int* __restrict__ counts,
                        int* __restrict__ lists, int* __restrict__ work) {
  __shared__ int lc[4];
  int t = threadIdx.x;
  if (t < 4) lc[t] = 0;
  __syncthreads();
  for (int i = t; i < B_N; i += 1024) {
    int a = act[i];
    int pos = atomicAdd(&lc[a], 1);
    lists[a * B_N + pos] = i;
  }
  __syncthreads();
  if (t < 4) counts[t] = lc[t];
  int t0 = (lc[0] + TILE_B - 1) >> 7, t1 = (lc[1] + TILE_B - 1) >> 7;
  int t2 = (lc[2] + TILE_B - 1) >> 7, t3 = (lc[3] + TILE_B - 1) >> 7;
  int T = t0 + t1 + t2 + t3;
  int total = T * NSPLIT;
  if (t == 0) work[0] = total;
  for (int i = t; i < total; i += 1024) {
    int lo = i & 7, q = i >> 3;
    int chi = q / T, j = q - chi * T;
    int c = (chi << 3) | lo;           // span 0..NSPLIT-1 (bijective: NSPLIT%8==0)
    int a, ty;
    if (j < t0)                { a = 0; ty = j; }
    else if (j < t0 + t1)      { a = 1; ty = j - t0; }
    else if (j < t0 + t1 + t2) { a = 2; ty = j - t0 - t1; }
    else                       { a = 3; ty = j - t0 - t1 - t2; }
    work[1 + i] = a | (ty << 2) | (c << 8);
  }
}

// ------------------------------------------------------------------
// F: routed flash attention. 512 threads / 8 waves; each wave owns one
//    16-sample M-tile. K is loaded DIRECTLY from global as x32 A-frag
//    operands (per-wave contiguous 4KB row-blocks -> L1 broadcast to
//    the block's 8 waves; span slab is L2-resident via XCD pinning).
//    Only V goes through LDS (double-buffered, KT=64 per barrier).
//    This halves LDS pipe load and frees K loads from all barriers.
//    S^T = K.Q^T (x32); permlane32+16 double-swap reshapes P into a
//    legal x32 A-frag so PV also runs at 16x16x32.
//    Padded D: no bounds checks in the K-loop; pad keys add exp(0)=1
//    to rowsum (subtracted in k_loss) and 0*V to O.
// ------------------------------------------------------------------
__launch_bounds__(512)
__global__ void k_flash(const unsigned short* __restrict__ kn,
                        const unsigned short* __restrict__ vt,
                        const unsigned short* __restrict__ qnb,
                        const int* __restrict__ counts,
                        const int* __restrict__ lists,
                        const int* __restrict__ work,
                        float* __restrict__ acc,
                        float* __restrict__ sume) {
  int total = work[0];
  if ((int)blockIdx.x >= total) return;
  int wi = work[1 + blockIdx.x];
  int a = wi & 3, ty = (wi >> 2) & 63, span = wi >> 8;
  int nb = counts[a];

  __shared__ unsigned short Vl[2][128 * VL_S];   // [buf][z][key]

  int t = threadIdx.x;
  int w = t >> 6, lane = t & 63;
  int lq = lane >> 4, ln = lane & 15;

  const unsigned short* kn_a = kn + (size_t)a * D_PAD * Z_N;
  const unsigned short* vt_a = vt + (size_t)a * Z_N * D_PAD;
  const int* list_a = lists + a * B_N;

  // Q fragment: lane holds Q[sample=ln][z = c*32 + lq*8 + j]
  int g0 = ty * TILE_B + w * 16 + ln;
  bool qvalid = g0 < nb;
  int si0 = qvalid ? list_a[g0] : 0;
  short8 qf[4];
#pragma unroll
  for (int c = 0; c < 4; ++c) {
    short8 s = (short8){0,0,0,0,0,0,0,0};
    if (qvalid) s = *(const short8*)(qnb + (size_t)si0 * Z_N + c * 32 + lq * 8);
    qf[c] = s;
  }

  f32x4 O[8];
#pragma unroll
  for (int zt = 0; zt < 8; ++zt) O[zt] = (f32x4){0.f, 0.f, 0.f, 0.f};
  float rs = 0.f;

  int d_base = span * SPAN;

  // K fragment per-lane base: row ln, z-offset lq*8
  const unsigned short* kK = kn_a + (size_t)ln * Z_N + lq * 8;

  // V staging: 512 threads x 2 stores of 16B cover 128 rows x 64 keys
  int sr0 = t >> 3, sk0 = (t & 7) * 8;   // rows sr0 and sr0+64

  uint4 vp0, vp1;

#define LOADV(d)                                                              \
  {                                                                           \
    vp0 = *(const uint4*)(vt_a + (size_t)sr0 * D_PAD + (d) + sk0);            \
    vp1 = *(const uint4*)(vt_a + (size_t)(sr0 + 64) * D_PAD + (d) + sk0);     \
  }
#define STOREV(p)                                                             \
  {                                                                           \
    *(uint4*)&Vl[p][sr0 * VL_S + sk0] = vp0;                                  \
    *(uint4*)&Vl[p][(sr0 + 64) * VL_S + sk0] = vp1;                           \
  }

  LOADV(d_base);
  STOREV(0);
  LOADV(d_base + KT);
  __syncthreads();

  int p = 0;
  for (int kt = 0; kt < NITER; ++kt) {
    int d0 = d_base + kt * KT;
    if (kt + 1 < NITER) {
      STOREV(p ^ 1);                              // commit tile kt+1
      if (kt + 2 < NITER) LOADV(d0 + 2 * KT)      // issue tile kt+2
    }

#pragma unroll
    for (int kk = 0; kk < 2; ++kk) {
      int dk = d0 + kk * 32;

      // S^T[key][sample] = Kn . Qn^T ; K frags straight from global
      f32x4 ST[2];
#pragma unroll
      for (int nt = 0; nt < 2; ++nt) {
        const unsigned short* kb = kK + (size_t)(dk + nt * 16) * Z_N;
        f32x4 s4 = (f32x4){0.f, 0.f, 0.f, 0.f};
#pragma unroll
        for (int c = 0; c < 4; ++c) {
          short8 kf = *(const short8*)(kb + c * 32);
          s4 = __builtin_amdgcn_mfma_f32_16x16x32_bf16(kf, qf[c], s4, 0, 0, 0);
        }
        ST[nt] = s4;
      }

      // exp (pad keys -> exp(0)=1, corrected in k_loss); per-lane rowsum
      float e0 = __expf(ST[0][0]), e1 = __expf(ST[0][1]);
      float e2 = __expf(ST[0][2]), e3 = __expf(ST[0][3]);
      float f0 = __expf(ST[1][0]), f1 = __expf(ST[1][1]);
      float f2 = __expf(ST[1][2]), f3 = __expf(ST[1][3]);
      rs += ((e0 + e1) + (e2 + e3)) + ((f0 + f1) + (f2 + f3));
      unsigned int s00, s01, s10, s11;
      asm("v_cvt_pk_bf16_f32 %0, %1, %2" : "=v"(s00) : "v"(e0), "v"(e1));
      asm("v_cvt_pk_bf16_f32 %0, %1, %2" : "=v"(s01) : "v"(e2), "v"(e3));
      asm("v_cvt_pk_bf16_f32 %0, %1, %2" : "=v"(s10) : "v"(f0), "v"(f1));
      asm("v_cvt_pk_bf16_f32 %0, %1, %2" : "=v"(s11) : "v"(f2), "v"(f3));

      // Redistribute P into x32 A-frag: (bit5=lq_hi, bit4=lq_lo, dw=(nt,h))
      //  -> (bit5'=nt, bit4'=lq_hi, dw'=(lq_lo,h)).
      plswap32(s00, s10);
      plswap32(s01, s11);
      plswap16(s00, s10);
      plswap16(s01, s11);
      union { unsigned int u[4]; short8 v; } pa;
      pa.u[0] = s00; pa.u[1] = s01; pa.u[2] = s10; pa.u[3] = s11;

      // O += P . V via x32 MFMA; B-frag: V[key = kk*32+lq*8+j][z = zt*16+ln]
#pragma unroll
      for (int zt = 0; zt < 8; ++zt) {
        short8 vf = *(const short8*)&Vl[p][(zt * 16 + ln) * VL_S + kk * 32 + lq * 8];
        O[zt] = __builtin_amdgcn_mfma_f32_16x16x32_bf16(pa.v, vf, O[zt], 0, 0, 0);
      }
    }

    __syncthreads();
    p ^= 1;
  }

  // rowsum finalize across the 4 quads (all hold partials for sample ln)
  rs += __shfl_xor(rs, 16);
  rs += __shfl_xor(rs, 32);

  if (lq == 0 && qvalid) atomicAdd(&sume[si0], rs);
#pragma unroll
  for (int r = 0; r < 4; ++r) {
    int g = ty * TILE_B + w * 16 + lq * 4 + r;
    if (g < nb) {
      int si = list_a[g];
      float* arow = acc + (size_t)si * Z_N + ln;
#pragma unroll
      for (int zt = 0; zt < 8; ++zt) atomicAdd(arow + zt * 16, O[zt][r]);
    }
  }
}

// ------------------------------------------------------------------
// F2: pred = acc/(sume - npad), accumulate pre-scaled squared error
//     directly into d_out (1 atomic/block; d_out memset to 0).
//     Each sample saw exactly D_PAD-D_N = 3248 pad keys (exp(0)=1 each).
// ------------------------------------------------------------------
__global__ void k_loss(const float* __restrict__ acc, const float* __restrict__ sume,
                       const float* __restrict__ nxt, float* __restrict__ out) {
  __shared__ float ls[4];
  int w = threadIdx.x >> 6, lane = threadIdx.x & 63;
  int row = blockIdx.x * 4 + w;
  float inv = 1.0f / (sume[row] - (float)(D_PAD - D_N));
  const float2 p2 = ((const float2*)(acc + (size_t)row * Z_N))[lane];
  const float2 n2 = ((const float2*)(nxt + (size_t)row * Z_N))[lane];
  float dx = p2.x * inv - n2.x, dy = p2.y * inv - n2.y;
  float s = dx * dx + dy * dy;
#pragma unroll
  for (int m = 1; m < 64; m <<= 1) s += __shfl_xor(s, m);
  if (lane == 0) ls[w] = s;
  __syncthreads();
  if (threadIdx.x == 0)
    atomicAdd(out, (ls[0] + ls[1] + ls[2] + ls[3]) * (1.0f / (float)(B_N * Z_N)));
}

// ------------------------------------------------------------------
// ws layout (bytes):
//  acc     @ 0           1,048,576   (zeroed)
//  sume    @ 1,048,576       8,192   (zeroed)
//  (pad)   @ 1,056,768          32   (zeroed)
//  counts  @ 1,056,784          16
//  lists   @ 1,056,800      32,768
//  work    @ 1,089,568       8,192
//  qnb     @ 1,097,760     524,288
//  kn bf16 @ 1,622,048  54,525,952   (A * D_PAD * Z)
//  vt bf16 @ 56,148,000 54,525,952   -> total ~110.7 MB
// ------------------------------------------------------------------
extern "C" void kernel_launch(void* const* d_in, const int* in_sizes, int n_in,
                              void* d_out, int out_size, void* d_ws, size_t ws_size,
                              hipStream_t stream) {
  const float* x    = (const float*)d_in[0];
  const float* nxt  = (const float*)d_in[1];
  const float* keys = (const float*)d_in[2];
  const float* vals = (const float*)d_in[3];
  const int*   act  = (const int*)d_in[4];

  char* ws = (char*)d_ws;
  float* acc    = (float*)(ws + 0);
  float* sume   = (float*)(ws + 1048576);
  int*   counts = (int*)(ws + 1056784);
  int*   lists  = (int*)(ws + 1056800);
  int*   work   = (int*)(ws + 1089568);
  unsigned short* qnb = (unsigned short*)(ws + 1097760);
  unsigned short* kn  = (unsigned short*)(ws + 1622048);
  unsigned short* vt  = (unsigned short*)(ws + 56148000);

  hipMemsetAsync(ws, 0, 1056784, stream);
  hipMemsetAsync(d_out, 0, 4, stream);

  k_route<<<1, 1024, 0, stream>>>(act, counts, lists, work);
  k_prep<<<NORM_BLOCKS + VT_BX * 2 * A_N, 256, 0, stream>>>(keys, x, vals, kn, qnb, vt);
  k_flash<<<1280, 512, 0, stream>>>(kn, vt, qnb, counts, lists, work, acc, sume);
  k_loss<<<512, 256, 0, stream>>>(acc, sume, nxt, (float*)d_out);
}

// Round 7
// 392.917 us; speedup vs baseline: 1.4758x; 1.4758x over previous
//
#include <hip/hip_runtime.h>
#include <stdint.h>

#define B_N 2048
#define Z_N 128
#define A_N 4
#define D_N 50000
#define D_PAD 51200    // 64 spans * 800 ; pad rows are exact zeros
#define EPS_F 1e-8f

#define TILE_B 128
#define KT 32
#define NSPLIT 64
#define SPAN 800       // 25*32 ; 64 spans cover 51200
#define NITER 25
#define KL_S 140       // 70 dwords == 6 (mod 32): K-read <=2-way (free)
#define VL_S 40        // 20 dwords: 16B-aligned rows, 2-way (free)

#define NORM_BLOCKS 51712   // (A_N*D_PAD + B_N)/4
#define VT_BX 800           // D_PAD/64

typedef __attribute__((ext_vector_type(8))) short short8;   // 8 bf16
typedef __attribute__((ext_vector_type(4))) float f32x4;
typedef __attribute__((ext_vector_type(2))) unsigned int u32x2;

__device__ __forceinline__ unsigned short f2bf(float f) {
  unsigned int u = __builtin_bit_cast(unsigned int, f);
  u += 0x7FFFu + ((u >> 16) & 1u);   // RNE
  return (unsigned short)(u >> 16);
}

__device__ __forceinline__ void plswap32(unsigned int& a, unsigned int& b) {
#if __has_builtin(__builtin_amdgcn_permlane32_swap)
  u32x2 r = __builtin_amdgcn_permlane32_swap(a, b, false, false);
  a = r[0]; b = r[1];
#else
  asm volatile("v_permlane32_swap_b32 %0, %1" : "+v"(a), "+v"(b));
#endif
}
__device__ __forceinline__ void plswap16(unsigned int& a, unsigned int& b) {
#if __has_builtin(__builtin_amdgcn_permlane16_swap)
  u32x2 r = __builtin_amdgcn_permlane16_swap(a, b, false, false);
  a = r[0]; b = r[1];
#else
  asm volatile("v_permlane16_swap_b32 %0, %1" : "+v"(a), "+v"(b));
#endif
}

// ------------------------------------------------------------------
// P: fused prep. Blocks [0, NORM_BLOCKS): normalize keys -> bf16
//    kn[a][d_pad][z] (pad rows = 0) and batch_x -> qnb.
//    Blocks >= NORM_BLOCKS: transpose vals -> bf16 vt[a][z][d_pad].
// ------------------------------------------------------------------
__global__ void k_prep(const float* __restrict__ keys, const float* __restrict__ x,
                       const float* __restrict__ vals,
                       unsigned short* __restrict__ kn, unsigned short* __restrict__ qnb,
                       unsigned short* __restrict__ vt) {
  if (blockIdx.x < NORM_BLOCKS) {
    int w = threadIdx.x >> 6, lane = threadIdx.x & 63;
    int row = blockIdx.x * 4 + w;      // < A*D_PAD + B
    const float* src;
    unsigned short* dst;
    if (row >= A_N * D_PAD) {          // query row
      int r = row - A_N * D_PAD;
      src = x + (size_t)r * Z_N;
      dst = qnb + (size_t)r * Z_N;
    } else {
      int a = row / D_PAD, d = row - a * D_PAD;
      dst = kn + (size_t)row * Z_N;
      if (d >= D_N) { ((unsigned int*)dst)[lane] = 0u; return; }   // zero pad row
      src = keys + ((size_t)a * D_N + d) * Z_N;
    }
    const float2 v = ((const float2*)src)[lane];
    float ss = v.x * v.x + v.y * v.y;
#pragma unroll
    for (int m = 1; m < 64; m <<= 1) ss += __shfl_xor(ss, m);
    float inv = 1.0f / (sqrtf(ss) + EPS_F);
    unsigned int packed = ((unsigned int)f2bf(v.y * inv) << 16) | f2bf(v.x * inv);
    ((unsigned int*)dst)[lane] = packed;
    return;
  }
  // ---- vals transpose ----
  __shared__ float tile[64][65];
  int b = blockIdx.x - NORM_BLOCKS;        // 0 .. VT_BX*2*A_N-1
  int bx = b % VT_BX, rest = b / VT_BX;
  int by = rest & 1, a = rest >> 1;
  int d0 = bx * 64, z0 = by * 64;
  int t = threadIdx.x;
  int r = t >> 4, c4 = (t & 15) * 4;
#pragma unroll
  for (int i = 0; i < 4; ++i) {
    int dr = r + i * 16, d = d0 + dr;
    float4 v = {0.f, 0.f, 0.f, 0.f};
    if (d < D_N) v = *(const float4*)(vals + ((size_t)a * D_N + d) * Z_N + z0 + c4);
    tile[dr][c4 + 0] = v.x; tile[dr][c4 + 1] = v.y;
    tile[dr][c4 + 2] = v.z; tile[dr][c4 + 3] = v.w;
  }
  __syncthreads();
  int zz = t >> 2, dg = (t & 3) * 16;
  union { unsigned short u[16]; uint4 q[2]; } pk;
#pragma unroll
  for (int j = 0; j < 16; ++j) pk.u[j] = f2bf(tile[dg + j][zz]);
  unsigned short* dst = vt + ((size_t)a * Z_N + z0 + zz) * D_PAD + d0 + dg;
  ((uint4*)dst)[0] = pk.q[0];
  ((uint4*)dst)[1] = pk.q[1];
}

// ------------------------------------------------------------------
// R: single-block routing + work list (TILE_B = 128). Item index
//    encodes XCD-pinned span-major order: i = (c&7) + 8*((c>>3)*T + j).
// ------------------------------------------------------------------
__global__ void k_route(const int* __restrict__ act, int* __restrict__ counts,
                        int* __restrict__ lists, int* __restrict__ work) {
  __shared__ int lc[4];
  int t = threadIdx.x;
  if (t < 4) lc[t] = 0;
  __syncthreads();
  for (int i = t; i < B_N; i += 1024) {
    int a = act[i];
    int pos = atomicAdd(&lc[a], 1);
    lists[a * B_N + pos] = i;
  }
  __syncthreads();
  if (t < 4) counts[t] = lc[t];
  int t0 = (lc[0] + TILE_B - 1) >> 7, t1 = (lc[1] + TILE_B - 1) >> 7;
  int t2 = (lc[2] + TILE_B - 1) >> 7, t3 = (lc[3] + TILE_B - 1) >> 7;
  int T = t0 + t1 + t2 + t3;
  int total = T * NSPLIT;
  if (t == 0) work[0] = total;
  for (int i = t; i < total; i += 1024) {
    int lo = i & 7, q = i >> 3;
    int chi = q / T, j = q - chi * T;
    int c = (chi << 3) | lo;           // span 0..NSPLIT-1 (bijective: NSPLIT%8==0)
    int a, ty;
    if (j < t0)                { a = 0; ty = j; }
    else if (j < t0 + t1)      { a = 1; ty = j - t0; }
    else if (j < t0 + t1 + t2) { a = 2; ty = j - t0 - t1; }
    else                       { a = 3; ty = j - t0 - t1 - t2; }
    work[1 + i] = a | (ty << 2) | (c << 8);
  }
}

// ------------------------------------------------------------------
// F: routed flash attention (round-3 structure, the measured best).
//    512 threads / 8 waves; each wave owns one 16-sample M-tile.
//    K+V double-buffered in LDS, single barrier per 32-key tile.
//    S^T = K.Q^T (x32); permlane32+16 double-swap reshapes P into a
//    legal x32 A-frag so PV also runs at 16x16x32.
//    s_setprio(1) wraps both MFMA clusters (T5): with 4 independent
//    blocks/CU the scheduler can prefer MFMA-entering waves over
//    staging/VALU waves of other blocks.
//    Padded D: no bounds checks in the K-loop; pad keys add exp(0)=1
//    to rowsum (subtracted in k_loss) and 0*V to O.
// ------------------------------------------------------------------
__launch_bounds__(512)
__global__ void k_flash(const unsigned short* __restrict__ kn,
                        const unsigned short* __restrict__ vt,
                        const unsigned short* __restrict__ qnb,
                        const int* __restrict__ counts,
                        const int* __restrict__ lists,
                        const int* __restrict__ work,
                        float* __restrict__ acc,
                        float* __restrict__ sume) {
  int total = work[0];
  if ((int)blockIdx.x >= total) return;
  int wi = work[1 + blockIdx.x];
  int a = wi & 3, ty = (wi >> 2) & 63, span = wi >> 8;
  int nb = counts[a];

  __shared__ unsigned short Kl[2][KT * KL_S];    // [buf][key][z]
  __shared__ unsigned short Vl[2][128 * VL_S];   // [buf][z][key]

  int t = threadIdx.x;
  int w = t >> 6, lane = t & 63;
  int lq = lane >> 4, ln = lane & 15;

  const unsigned short* kn_a = kn + (size_t)a * D_PAD * Z_N;
  const unsigned short* vt_a = vt + (size_t)a * Z_N * D_PAD;
  const int* list_a = lists + a * B_N;

  // Q fragment: lane holds Q[sample=ln][z = c*32 + lq*8 + j]
  int g0 = ty * TILE_B + w * 16 + ln;
  bool qvalid = g0 < nb;
  int si0 = qvalid ? list_a[g0] : 0;
  short8 qf[4];
#pragma unroll
  for (int c = 0; c < 4; ++c) {
    short8 s = (short8){0,0,0,0,0,0,0,0};
    if (qvalid) s = *(const short8*)(qnb + (size_t)si0 * Z_N + c * 32 + lq * 8);
    qf[c] = s;
  }

  f32x4 O[8];
#pragma unroll
  for (int zt = 0; zt < 8; ++zt) O[zt] = (f32x4){0.f, 0.f, 0.f, 0.f};
  float rs = 0.f;

  int d_base = span * SPAN;
  int sk_key = t >> 4, sk_z = (t & 15) * 8;      // K staging: 16B/thread
  int sv_z = t >> 2, sv_k = (t & 3) * 8;         // V staging: 16B/thread

  uint4 kp, vp;

#define LOAD_TILE(d)                                                          \
  {                                                                           \
    kp = *(const uint4*)(kn_a + (size_t)((d) + sk_key) * Z_N + sk_z);         \
    vp = *(const uint4*)(vt_a + (size_t)sv_z * D_PAD + (d) + sv_k);           \
  }
#define STORE_TILE(p)                                                         \
  {                                                                           \
    *(uint4*)&Kl[p][sk_key * KL_S + sk_z] = kp;                               \
    *(uint4*)&Vl[p][sv_z * VL_S + sv_k] = vp;                                 \
  }

  LOAD_TILE(d_base);
  STORE_TILE(0);
  LOAD_TILE(d_base + KT);
  __syncthreads();

  int p = 0;
  for (int kt = 0; kt < NITER; ++kt) {
    int d0 = d_base + kt * KT;
    if (kt + 1 < NITER) {
      STORE_TILE(p ^ 1);                         // commit tile kt+1
      if (kt + 2 < NITER) LOAD_TILE(d0 + 2 * KT) // issue tile kt+2
    }

    // S^T[key][sample] = Kn . Qn^T
    f32x4 ST[2];
    __builtin_amdgcn_s_setprio(1);
#pragma unroll
    for (int nt = 0; nt < 2; ++nt) {
      short8 kf[4];
#pragma unroll
      for (int c = 0; c < 4; ++c)
        kf[c] = *(const short8*)&Kl[p][(nt * 16 + ln) * KL_S + c * 32 + lq * 8];
      f32x4 s4 = (f32x4){0.f, 0.f, 0.f, 0.f};
#pragma unroll
      for (int c = 0; c < 4; ++c)
        s4 = __builtin_amdgcn_mfma_f32_16x16x32_bf16(kf[c], qf[c], s4, 0, 0, 0);
      ST[nt] = s4;
    }
    __builtin_amdgcn_s_setprio(0);

    // exp (pad keys -> exp(0)=1, corrected in k_loss); per-lane rowsum;
    // pack bf16 pairs: dword (nt,h) = keys nt*16+lq*4+2h+{0,1}
    unsigned int s00, s01, s10, s11;
    {
      float e0 = __expf(ST[0][0]), e1 = __expf(ST[0][1]);
      float e2 = __expf(ST[0][2]), e3 = __expf(ST[0][3]);
      float f0 = __expf(ST[1][0]), f1 = __expf(ST[1][1]);
      float f2 = __expf(ST[1][2]), f3 = __expf(ST[1][3]);
      rs += ((e0 + e1) + (e2 + e3)) + ((f0 + f1) + (f2 + f3));
      asm("v_cvt_pk_bf16_f32 %0, %1, %2" : "=v"(s00) : "v"(e0), "v"(e1));
      asm("v_cvt_pk_bf16_f32 %0, %1, %2" : "=v"(s01) : "v"(e2), "v"(e3));
      asm("v_cvt_pk_bf16_f32 %0, %1, %2" : "=v"(s10) : "v"(f0), "v"(f1));
      asm("v_cvt_pk_bf16_f32 %0, %1, %2" : "=v"(s11) : "v"(f2), "v"(f3));
    }

    // Redistribute P into x32 A-frag: (bit5=lq_hi, bit4=lq_lo, dw=(nt,h))
    //  -> (bit5'=nt, bit4'=lq_hi, dw'=(lq_lo,h)).
    plswap32(s00, s10);
    plswap32(s01, s11);
    plswap16(s00, s10);
    plswap16(s01, s11);
    union { unsigned int u[4]; short8 v; } pa;
    pa.u[0] = s00; pa.u[1] = s01; pa.u[2] = s10; pa.u[3] = s11;

    // O += P . V via x32 MFMA; B-frag: V[key = lq*8+j][z = zt*16+ln]
    __builtin_amdgcn_s_setprio(1);
#pragma unroll
    for (int zt = 0; zt < 8; ++zt) {
      short8 vf = *(const short8*)&Vl[p][(zt * 16 + ln) * VL_S + lq * 8];
      O[zt] = __builtin_amdgcn_mfma_f32_16x16x32_bf16(pa.v, vf, O[zt], 0, 0, 0);
    }
    __builtin_amdgcn_s_setprio(0);

    __syncthreads();
    p ^= 1;
  }

  // rowsum finalize across the 4 quads (all hold partials for sample ln)
  rs += __shfl_xor(rs, 16);
  rs += __shfl_xor(rs, 32);

  if (lq == 0 && qvalid) atomicAdd(&sume[si0], rs);
#pragma unroll
  for (int r = 0; r < 4; ++r) {
    int g = ty * TILE_B + w * 16 + lq * 4 + r;
    if (g < nb) {
      int si = list_a[g];
      float* arow = acc + (size_t)si * Z_N + ln;
#pragma unroll
      for (int zt = 0; zt < 8; ++zt) atomicAdd(arow + zt * 16, O[zt][r]);
    }
  }
}

// ------------------------------------------------------------------
// F2: pred = acc/(sume - npad), accumulate pre-scaled squared error
//     directly into d_out (1 atomic/block; d_out memset to 0).
//     Each sample saw exactly D_PAD-D_N = 1200 pad keys (exp(0)=1 each).
// ------------------------------------------------------------------
__global__ void k_loss(const float* __restrict__ acc, const float* __restrict__ sume,
                       const float* __restrict__ nxt, float* __restrict__ out) {
  __shared__ float ls[4];
  int w = threadIdx.x >> 6, lane = threadIdx.x & 63;
  int row = blockIdx.x * 4 + w;
  float inv = 1.0f / (sume[row] - (float)(D_PAD - D_N));
  const float2 p2 = ((const float2*)(acc + (size_t)row * Z_N))[lane];
  const float2 n2 = ((const float2*)(nxt + (size_t)row * Z_N))[lane];
  float dx = p2.x * inv - n2.x, dy = p2.y * inv - n2.y;
  float s = dx * dx + dy * dy;
#pragma unroll
  for (int m = 1; m < 64; m <<= 1) s += __shfl_xor(s, m);
  if (lane == 0) ls[w] = s;
  __syncthreads();
  if (threadIdx.x == 0)
    atomicAdd(out, (ls[0] + ls[1] + ls[2] + ls[3]) * (1.0f / (float)(B_N * Z_N)));
}

// ------------------------------------------------------------------
// ws layout (bytes):
//  acc     @ 0           1,048,576   (zeroed)
//  sume    @ 1,048,576       8,192   (zeroed)
//  (pad)   @ 1,056,768          32   (zeroed)
//  counts  @ 1,056,784          16
//  lists   @ 1,056,800      32,768
//  work    @ 1,089,568       8,192
//  qnb     @ 1,097,760     524,288
//  kn bf16 @ 1,622,048  52,428,800   (A * D_PAD * Z)
//  vt bf16 @ 54,050,848 52,428,800   -> total ~106.5 MB
// ------------------------------------------------------------------
extern "C" void kernel_launch(void* const* d_in, const int* in_sizes, int n_in,
                              void* d_out, int out_size, void* d_ws, size_t ws_size,
                              hipStream_t stream) {
  const float* x    = (const float*)d_in[0];
  const float* nxt  = (const float*)d_in[1];
  const float* keys = (const float*)d_in[2];
  const float* vals = (const float*)d_in[3];
  const int*   act  = (const int*)d_in[4];

  char* ws = (char*)d_ws;
  float* acc    = (float*)(ws + 0);
  float* sume   = (float*)(ws + 1048576);
  int*   counts = (int*)(ws + 1056784);
  int*   lists  = (int*)(ws + 1056800);
  int*   work   = (int*)(ws + 1089568);
  unsigned short* qnb = (unsigned short*)(ws + 1097760);
  unsigned short* kn  = (unsigned short*)(ws + 1622048);
  unsigned short* vt  = (unsigned short*)(ws + 54050848);

  hipMemsetAsync(ws, 0, 1056784, stream);
  hipMemsetAsync(d_out, 0, 4, stream);

  k_route<<<1, 1024, 0, stream>>>(act, counts, lists, work);
  k_prep<<<NORM_BLOCKS + VT_BX * 2 * A_N, 256, 0, stream>>>(keys, x, vals, kn, qnb, vt);
  k_flash<<<1216, 512, 0, stream>>>(kn, vt, qnb, counts, lists, work, acc, sume);
  k_loss<<<512, 256, 0, stream>>>(acc, sume, nxt, (float*)d_out);
}

// Round 8
// 365.654 us; speedup vs baseline: 1.5858x; 1.0746x over previous
//
#include <hip/hip_runtime.h>
#include <stdint.h>

#define B_N 2048
#define Z_N 128
#define A_N 4
#define D_N 50000
#define D_PAD 51200    // 64 spans * 800 ; pad rows are exact zeros
#define EPS_F 1e-8f

#define TILE_B 128
#define KT 32
#define NSPLIT 64
#define SPAN 800       // 25*32 ; 64 spans cover 51200
#define NITER 25
#define KL_S 140       // 70 dwords == 6 (mod 32): K-read <=2-way (free)
#define VL_S 40        // 20 dwords: 16B-aligned rows, 2-way (free)

#define NROW_BLOCKS 25856   // (A_N*D_PAD + B_N) / 8 rows per block
#define VT_BX 800           // D_PAD/64
#define VT_BLOCKS 6400      // VT_BX * 2 * A_N

typedef __attribute__((ext_vector_type(8))) short short8;   // 8 bf16
typedef __attribute__((ext_vector_type(4))) float f32x4;
typedef __attribute__((ext_vector_type(2))) unsigned int u32x2;

__device__ __forceinline__ unsigned short f2bf(float f) {
  unsigned int u = __builtin_bit_cast(unsigned int, f);
  u += 0x7FFFu + ((u >> 16) & 1u);   // RNE
  return (unsigned short)(u >> 16);
}

__device__ __forceinline__ void plswap32(unsigned int& a, unsigned int& b) {
#if __has_builtin(__builtin_amdgcn_permlane32_swap)
  u32x2 r = __builtin_amdgcn_permlane32_swap(a, b, false, false);
  a = r[0]; b = r[1];
#else
  asm volatile("v_permlane32_swap_b32 %0, %1" : "+v"(a), "+v"(b));
#endif
}
__device__ __forceinline__ void plswap16(unsigned int& a, unsigned int& b) {
#if __has_builtin(__builtin_amdgcn_permlane16_swap)
  u32x2 r = __builtin_amdgcn_permlane16_swap(a, b, false, false);
  a = r[0]; b = r[1];
#else
  asm volatile("v_permlane16_swap_b32 %0, %1" : "+v"(a), "+v"(b));
#endif
}

// ------------------------------------------------------------------
// P: fused prep + routing (3 block ranges, uniform branch per block).
//  [0, NROW_BLOCKS): normalize keys -> bf16 kn[a][d_pad][z] (pad rows
//    = 0) and batch_x -> qnb. float4 loads (16B/lane), 2 rows/wave.
//  [NROW_BLOCKS, +VT_BLOCKS): transpose vals -> bf16 vt[a][z][d_pad].
//  last block: routing — per-action lists + XCD-pinned span-major
//    work list  i = (c&7) + 8*((c>>3)*T + j).
// ------------------------------------------------------------------
__global__ void k_prep(const float* __restrict__ keys, const float* __restrict__ x,
                       const float* __restrict__ vals, const int* __restrict__ act,
                       unsigned short* __restrict__ kn, unsigned short* __restrict__ qnb,
                       unsigned short* __restrict__ vt,
                       int* __restrict__ counts, int* __restrict__ lists,
                       int* __restrict__ work) {
  __shared__ float tile[64][65];
  if (blockIdx.x < NROW_BLOCKS) {
    // ---- row normalize: 4 waves x 2 rows, float4/lane ----
    int w = threadIdx.x >> 6, lane = threadIdx.x & 63;
    int l32 = lane & 31;
    int row = blockIdx.x * 8 + w * 2 + (lane >> 5);   // < A*D_PAD + B
    const float* src;
    unsigned short* dst;
    if (row >= A_N * D_PAD) {          // query row
      int r = row - A_N * D_PAD;
      src = x + (size_t)r * Z_N;
      dst = qnb + (size_t)r * Z_N;
    } else {
      int a = row / D_PAD, d = row - a * D_PAD;
      dst = kn + (size_t)row * Z_N;
      if (d >= D_N) {                  // zero pad row
        ((u32x2*)dst)[l32] = (u32x2){0u, 0u};
        return;
      }
      src = keys + ((size_t)a * D_N + d) * Z_N;
    }
    const float4 v = ((const float4*)src)[l32];
    float ss = v.x * v.x + v.y * v.y + v.z * v.z + v.w * v.w;
#pragma unroll
    for (int m = 1; m < 32; m <<= 1) ss += __shfl_xor(ss, m);
    float inv = 1.0f / (sqrtf(ss) + EPS_F);
    u32x2 pk;
    pk[0] = ((unsigned int)f2bf(v.y * inv) << 16) | f2bf(v.x * inv);
    pk[1] = ((unsigned int)f2bf(v.w * inv) << 16) | f2bf(v.z * inv);
    ((u32x2*)dst)[l32] = pk;
    return;
  }
  if (blockIdx.x < NROW_BLOCKS + VT_BLOCKS) {
    // ---- vals transpose ----
    int b = blockIdx.x - NROW_BLOCKS;        // 0 .. VT_BLOCKS-1
    int bx = b % VT_BX, rest = b / VT_BX;
    int by = rest & 1, a = rest >> 1;
    int d0 = bx * 64, z0 = by * 64;
    int t = threadIdx.x;
    int r = t >> 4, c4 = (t & 15) * 4;
#pragma unroll
    for (int i = 0; i < 4; ++i) {
      int dr = r + i * 16, d = d0 + dr;
      float4 v = {0.f, 0.f, 0.f, 0.f};
      if (d < D_N) v = *(const float4*)(vals + ((size_t)a * D_N + d) * Z_N + z0 + c4);
      tile[dr][c4 + 0] = v.x; tile[dr][c4 + 1] = v.y;
      tile[dr][c4 + 2] = v.z; tile[dr][c4 + 3] = v.w;
    }
    __syncthreads();
    int zz = t >> 2, dg = (t & 3) * 16;
    union { unsigned short u[16]; uint4 q[2]; } pk;
#pragma unroll
    for (int j = 0; j < 16; ++j) pk.u[j] = f2bf(tile[dg + j][zz]);
    unsigned short* dst = vt + ((size_t)a * Z_N + z0 + zz) * D_PAD + d0 + dg;
    ((uint4*)dst)[0] = pk.q[0];
    ((uint4*)dst)[1] = pk.q[1];
    return;
  }
  // ---- routing (single block) ----
  int* lc = (int*)tile;
  int t = threadIdx.x;
  if (t < 4) lc[t] = 0;
  __syncthreads();
  for (int i = t; i < B_N; i += 256) {
    int a = act[i];
    int pos = atomicAdd(&lc[a], 1);
    lists[a * B_N + pos] = i;
  }
  __syncthreads();
  if (t < 4) counts[t] = lc[t];
  int t0 = (lc[0] + TILE_B - 1) >> 7, t1 = (lc[1] + TILE_B - 1) >> 7;
  int t2 = (lc[2] + TILE_B - 1) >> 7, t3 = (lc[3] + TILE_B - 1) >> 7;
  int T = t0 + t1 + t2 + t3;
  int total = T * NSPLIT;
  if (t == 0) work[0] = total;
  for (int i = t; i < total; i += 256) {
    int lo = i & 7, q = i >> 3;
    int chi = q / T, j = q - chi * T;
    int c = (chi << 3) | lo;           // span 0..NSPLIT-1 (bijective: NSPLIT%8==0)
    int a, ty;
    if (j < t0)                { a = 0; ty = j; }
    else if (j < t0 + t1)      { a = 1; ty = j - t0; }
    else if (j < t0 + t1 + t2) { a = 2; ty = j - t0 - t1; }
    else                       { a = 3; ty = j - t0 - t1 - t2; }
    work[1 + i] = a | (ty << 2) | (c << 8);
  }
}

// ------------------------------------------------------------------
// F: routed flash attention (round-3 structure, the measured best —
//    121 us; NO setprio: A/B r3 vs r7 showed setprio costs +19 us in
//    this barrier-locked 2-phase loop).
//    512 threads / 8 waves; each wave owns one 16-sample M-tile.
//    K+V double-buffered in LDS, single barrier per 32-key tile.
//    S^T = K.Q^T (x32); permlane32+16 double-swap reshapes P into a
//    legal x32 A-frag so PV also runs at 16x16x32.
//    Padded D: no bounds checks in the K-loop; pad keys add exp(0)=1
//    to rowsum (subtracted in k_loss) and 0*V to O.
// ------------------------------------------------------------------
__launch_bounds__(512)
__global__ void k_flash(const unsigned short* __restrict__ kn,
                        const unsigned short* __restrict__ vt,
                        const unsigned short* __restrict__ qnb,
                        const int* __restrict__ counts,
                        const int* __restrict__ lists,
                        const int* __restrict__ work,
                        float* __restrict__ acc,
                        float* __restrict__ sume) {
  int total = work[0];
  if ((int)blockIdx.x >= total) return;
  int wi = work[1 + blockIdx.x];
  int a = wi & 3, ty = (wi >> 2) & 63, span = wi >> 8;
  int nb = counts[a];

  __shared__ unsigned short Kl[2][KT * KL_S];    // [buf][key][z]
  __shared__ unsigned short Vl[2][128 * VL_S];   // [buf][z][key]

  int t = threadIdx.x;
  int w = t >> 6, lane = t & 63;
  int lq = lane >> 4, ln = lane & 15;

  const unsigned short* kn_a = kn + (size_t)a * D_PAD * Z_N;
  const unsigned short* vt_a = vt + (size_t)a * Z_N * D_PAD;
  const int* list_a = lists + a * B_N;

  // Q fragment: lane holds Q[sample=ln][z = c*32 + lq*8 + j]
  int g0 = ty * TILE_B + w * 16 + ln;
  bool qvalid = g0 < nb;
  int si0 = qvalid ? list_a[g0] : 0;
  short8 qf[4];
#pragma unroll
  for (int c = 0; c < 4; ++c) {
    short8 s = (short8){0,0,0,0,0,0,0,0};
    if (qvalid) s = *(const short8*)(qnb + (size_t)si0 * Z_N + c * 32 + lq * 8);
    qf[c] = s;
  }

  f32x4 O[8];
#pragma unroll
  for (int zt = 0; zt < 8; ++zt) O[zt] = (f32x4){0.f, 0.f, 0.f, 0.f};
  float rs = 0.f;

  int d_base = span * SPAN;
  int sk_key = t >> 4, sk_z = (t & 15) * 8;      // K staging: 16B/thread
  int sv_z = t >> 2, sv_k = (t & 3) * 8;         // V staging: 16B/thread

  uint4 kp, vp;

#define LOAD_TILE(d)                                                          \
  {                                                                           \
    kp = *(const uint4*)(kn_a + (size_t)((d) + sk_key) * Z_N + sk_z);         \
    vp = *(const uint4*)(vt_a + (size_t)sv_z * D_PAD + (d) + sv_k);           \
  }
#define STORE_TILE(p)                                                         \
  {                                                                           \
    *(uint4*)&Kl[p][sk_key * KL_S + sk_z] = kp;                               \
    *(uint4*)&Vl[p][sv_z * VL_S + sv_k] = vp;                                 \
  }

  LOAD_TILE(d_base);
  STORE_TILE(0);
  LOAD_TILE(d_base + KT);
  __syncthreads();

  int p = 0;
  for (int kt = 0; kt < NITER; ++kt) {
    int d0 = d_base + kt * KT;
    if (kt + 1 < NITER) {
      STORE_TILE(p ^ 1);                         // commit tile kt+1
      if (kt + 2 < NITER) LOAD_TILE(d0 + 2 * KT) // issue tile kt+2
    }

    // S^T[key][sample] = Kn . Qn^T
    f32x4 ST[2];
#pragma unroll
    for (int nt = 0; nt < 2; ++nt) {
      short8 kf[4];
#pragma unroll
      for (int c = 0; c < 4; ++c)
        kf[c] = *(const short8*)&Kl[p][(nt * 16 + ln) * KL_S + c * 32 + lq * 8];
      f32x4 s4 = (f32x4){0.f, 0.f, 0.f, 0.f};
#pragma unroll
      for (int c = 0; c < 4; ++c)
        s4 = __builtin_amdgcn_mfma_f32_16x16x32_bf16(kf[c], qf[c], s4, 0, 0, 0);
      ST[nt] = s4;
    }

    // exp (pad keys -> exp(0)=1, corrected in k_loss); per-lane rowsum;
    // pack bf16 pairs: dword (nt,h) = keys nt*16+lq*4+2h+{0,1}
    unsigned int s00, s01, s10, s11;
    {
      float e0 = __expf(ST[0][0]), e1 = __expf(ST[0][1]);
      float e2 = __expf(ST[0][2]), e3 = __expf(ST[0][3]);
      float f0 = __expf(ST[1][0]), f1 = __expf(ST[1][1]);
      float f2 = __expf(ST[1][2]), f3 = __expf(ST[1][3]);
      rs += ((e0 + e1) + (e2 + e3)) + ((f0 + f1) + (f2 + f3));
      asm("v_cvt_pk_bf16_f32 %0, %1, %2" : "=v"(s00) : "v"(e0), "v"(e1));
      asm("v_cvt_pk_bf16_f32 %0, %1, %2" : "=v"(s01) : "v"(e2), "v"(e3));
      asm("v_cvt_pk_bf16_f32 %0, %1, %2" : "=v"(s10) : "v"(f0), "v"(f1));
      asm("v_cvt_pk_bf16_f32 %0, %1, %2" : "=v"(s11) : "v"(f2), "v"(f3));
    }

    // Redistribute P into x32 A-frag: (bit5=lq_hi, bit4=lq_lo, dw=(nt,h))
    //  -> (bit5'=nt, bit4'=lq_hi, dw'=(lq_lo,h)).
    plswap32(s00, s10);
    plswap32(s01, s11);
    plswap16(s00, s10);
    plswap16(s01, s11);
    union { unsigned int u[4]; short8 v; } pa;
    pa.u[0] = s00; pa.u[1] = s01; pa.u[2] = s10; pa.u[3] = s11;

    // O += P . V via x32 MFMA; B-frag: V[key = lq*8+j][z = zt*16+ln]
#pragma unroll
    for (int zt = 0; zt < 8; ++zt) {
      short8 vf = *(const short8*)&Vl[p][(zt * 16 + ln) * VL_S + lq * 8];
      O[zt] = __builtin_amdgcn_mfma_f32_16x16x32_bf16(pa.v, vf, O[zt], 0, 0, 0);
    }

    __syncthreads();
    p ^= 1;
  }

  // rowsum finalize across the 4 quads (all hold partials for sample ln)
  rs += __shfl_xor(rs, 16);
  rs += __shfl_xor(rs, 32);

  if (lq == 0 && qvalid) atomicAdd(&sume[si0], rs);
#pragma unroll
  for (int r = 0; r < 4; ++r) {
    int g = ty * TILE_B + w * 16 + lq * 4 + r;
    if (g < nb) {
      int si = list_a[g];
      float* arow = acc + (size_t)si * Z_N + ln;
#pragma unroll
      for (int zt = 0; zt < 8; ++zt) atomicAdd(arow + zt * 16, O[zt][r]);
    }
  }
}

// ------------------------------------------------------------------
// F2: pred = acc/(sume - npad), accumulate pre-scaled squared error
//     directly into d_out (1 atomic/block; d_out memset to 0).
//     Each sample saw exactly D_PAD-D_N = 1200 pad keys (exp(0)=1 each).
// ------------------------------------------------------------------
__global__ void k_loss(const float* __restrict__ acc, const float* __restrict__ sume,
                       const float* __restrict__ nxt, float* __restrict__ out) {
  __shared__ float ls[4];
  int w = threadIdx.x >> 6, lane = threadIdx.x & 63;
  int row = blockIdx.x * 4 + w;
  float inv = 1.0f / (sume[row] - (float)(D_PAD - D_N));
  const float2 p2 = ((const float2*)(acc + (size_t)row * Z_N))[lane];
  const float2 n2 = ((const float2*)(nxt + (size_t)row * Z_N))[lane];
  float dx = p2.x * inv - n2.x, dy = p2.y * inv - n2.y;
  float s = dx * dx + dy * dy;
#pragma unroll
  for (int m = 1; m < 64; m <<= 1) s += __shfl_xor(s, m);
  if (lane == 0) ls[w] = s;
  __syncthreads();
  if (threadIdx.x == 0)
    atomicAdd(out, (ls[0] + ls[1] + ls[2] + ls[3]) * (1.0f / (float)(B_N * Z_N)));
}

// ------------------------------------------------------------------
// ws layout (bytes):
//  acc     @ 0           1,048,576   (zeroed)
//  sume    @ 1,048,576       8,192   (zeroed)
//  (pad)   @ 1,056,768          32   (zeroed)
//  counts  @ 1,056,784          16
//  lists   @ 1,056,800      32,768
//  work    @ 1,089,568       8,192
//  qnb     @ 1,097,760     524,288
//  kn bf16 @ 1,622,048  52,428,800   (A * D_PAD * Z)
//  vt bf16 @ 54,050,848 52,428,800   -> total ~106.5 MB
// ------------------------------------------------------------------
extern "C" void kernel_launch(void* const* d_in, const int* in_sizes, int n_in,
                              void* d_out, int out_size, void* d_ws, size_t ws_size,
                              hipStream_t stream) {
  const float* x    = (const float*)d_in[0];
  const float* nxt  = (const float*)d_in[1];
  const float* keys = (const float*)d_in[2];
  const float* vals = (const float*)d_in[3];
  const int*   act  = (const int*)d_in[4];

  char* ws = (char*)d_ws;
  float* acc    = (float*)(ws + 0);
  float* sume   = (float*)(ws + 1048576);
  int*   counts = (int*)(ws + 1056784);
  int*   lists  = (int*)(ws + 1056800);
  int*   work   = (int*)(ws + 1089568);
  unsigned short* qnb = (unsigned short*)(ws + 1097760);
  unsigned short* kn  = (unsigned short*)(ws + 1622048);
  unsigned short* vt  = (unsigned short*)(ws + 54050848);

  hipMemsetAsync(ws, 0, 1056784, stream);
  hipMemsetAsync(d_out, 0, 4, stream);

  k_prep<<<NROW_BLOCKS + VT_BLOCKS + 1, 256, 0, stream>>>(
      keys, x, vals, act, kn, qnb, vt, counts, lists, work);
  k_flash<<<1216, 512, 0, stream>>>(kn, vt, qnb, counts, lists, work, acc, sume);
  k_loss<<<512, 256, 0, stream>>>(acc, sume, nxt, (float*)d_out);
}